// Round 7
// baseline (211.995 us; speedup 1.0000x reference)
//
#include <hip/hip_runtime.h>
#include <hip/hip_bf16.h>

typedef __attribute__((ext_vector_type(8))) short bf16x8;
typedef __attribute__((ext_vector_type(4))) float f32x4;
typedef __attribute__((ext_vector_type(16))) float f32x16;
typedef __attribute__((ext_vector_type(2))) unsigned int u32x2;

__device__ __forceinline__ float fexp2(float x) { return __builtin_amdgcn_exp2f(x); }

__device__ __forceinline__ ushort f2bf(float x) {
    union { float f; unsigned u; } c; c.f = x;
    unsigned r = c.u + 0x7fff + ((c.u >> 16) & 1);
    return (ushort)(r >> 16);
}

__device__ __forceinline__ unsigned cvtpk(float lo, float hi) {
    unsigned r;
    asm("v_cvt_pk_bf16_f32 %0, %1, %2" : "=v"(r) : "v"(lo), "v"(hi));
    return r;
}

__device__ __forceinline__ void gload16(const void* g, void* l) {
    __builtin_amdgcn_global_load_lds((const __attribute__((address_space(1))) void*)g,
                                     (__attribute__((address_space(3))) void*)l, 16, 0, 0);
}

__device__ __forceinline__ void blockbar() {
    asm volatile("" ::: "memory");
    __builtin_amdgcn_s_barrier();
    asm volatile("" ::: "memory");
}

// ---------------- f32 -> bf16 converts ----------------
__global__ void cvt_f32_bf16(const float* __restrict__ in, ushort* __restrict__ out, int n4) {
    int i = blockIdx.x * blockDim.x + threadIdx.x;
    int stride = gridDim.x * blockDim.x;
    for (; i < n4; i += stride) {
        float4 v = ((const float4*)in)[i];
        ushort4 o;
        o.x = f2bf(v.x); o.y = f2bf(v.y); o.z = f2bf(v.z); o.w = f2bf(v.w);
        ((ushort4*)out)[i] = o;
    }
}

__global__ void cvt_w4(const float* __restrict__ a, const float* __restrict__ b,
                       const float* __restrict__ c, const float* __restrict__ d,
                       ushort* __restrict__ oq, ushort* __restrict__ ow) {
    const int N4 = 262144;
    int i = blockIdx.x * blockDim.x + threadIdx.x;
    int stride = gridDim.x * blockDim.x;
    for (; i < 4 * N4; i += stride) {
        int sel = i >> 18, local = i & (N4 - 1);
        const float* src = (sel == 0) ? a : (sel == 1) ? b : (sel == 2) ? c : d;
        float4 v = ((const float4*)src)[local];
        ushort4 o;
        o.x = f2bf(v.x); o.y = f2bf(v.y); o.z = f2bf(v.z); o.w = f2bf(v.w);
        if (sel < 3) ((ushort4*)oq)[sel * N4 + local] = o;
        else         ((ushort4*)ow)[local] = o;
    }
}

// ---------------- m97-style bf16 GEMM ----------------
// MODE 0: QKV-cat; Q third pre-scaled by 0.125*log2(e) for exp2-domain attn
template<int MODE>
__global__ __launch_bounds__(256)
void gemm_m97(const ushort* __restrict__ A, const ushort* __restrict__ Bt,
              const float* __restrict__ bias0, const float* __restrict__ bias1,
              const float* __restrict__ bias2,
              ushort* __restrict__ outb, float* __restrict__ outf,
              int M, int N, int K) {
    __shared__ ushort As[128 * 32];
    __shared__ ushort Bs[128 * 32];
    const int t = threadIdx.x, lane = t & 63, w = t >> 6;
    const int wr = w >> 1, wc = w & 1;
    const int l15 = lane & 15, lg = lane >> 4;
    const int nwg = gridDim.x * gridDim.y;
    const int bid = blockIdx.y * gridDim.x + blockIdx.x;
    const int swz = (bid & 7) * (nwg >> 3) + (bid >> 3);
    const int m0 = (swz / gridDim.x) * 128, n0 = (swz % gridDim.x) * 128;
    const int srow = lane >> 2;
    const int sg = (lane & 3) ^ ((lane >> 2) & 3);

    f32x4 acc[4][4] = {};

    for (int k0 = 0; k0 < K; k0 += 32) {
#pragma unroll
        for (int i = 0; i < 2; i++) {
            int c = i * 4 + w;
            const ushort* as = A + (size_t)(m0 + c * 16 + srow) * K + k0 + sg * 8;
            const ushort* bs = Bt + (size_t)(n0 + c * 16 + srow) * K + k0 + sg * 8;
            gload16(as, &As[c * 512]);
            gload16(bs, &Bs[c * 512]);
        }
        __syncthreads();
        bf16x8 af[4], bfr[4];
#pragma unroll
        for (int mi = 0; mi < 4; mi++) {
            int row = wr * 64 + mi * 16 + l15;
            af[mi] = *(const bf16x8*)&As[row * 32 + ((lg ^ (row & 3)) << 3)];
        }
#pragma unroll
        for (int ni = 0; ni < 4; ni++) {
            int row = wc * 64 + ni * 16 + l15;
            bfr[ni] = *(const bf16x8*)&Bs[row * 32 + ((lg ^ (row & 3)) << 3)];
        }
        __builtin_amdgcn_s_setprio(1);
#pragma unroll
        for (int mi = 0; mi < 4; mi++)
#pragma unroll
            for (int ni = 0; ni < 4; ni++)
                acc[mi][ni] = __builtin_amdgcn_mfma_f32_16x16x32_bf16(af[mi], bfr[ni], acc[mi][ni], 0, 0, 0);
        __builtin_amdgcn_s_setprio(0);
        __syncthreads();
    }

#pragma unroll
    for (int mi = 0; mi < 4; mi++)
#pragma unroll
        for (int ni = 0; ni < 4; ni++)
#pragma unroll
            for (int r = 0; r < 4; r++) {
                int gm = m0 + wr * 64 + mi * 16 + lg * 4 + r;
                int gn = n0 + wc * 64 + ni * 16 + l15;
                if (MODE == 0) {
                    const float* bp = (gn < 1024) ? bias0 : ((gn < 2048) ? bias1 : bias2);
                    float v = acc[mi][ni][r] + bp[gn & 1023];
                    if (gn < 1024) v *= 0.18033688011f;  // 0.125 * log2(e)
                    int proj = gn >> 10, nn = gn & 1023;
                    int h = nn >> 6, d = nn & 63;
                    int b = gm >> 11, s = gm & 2047;
                    outb[(size_t)proj * 8388608 + ((((size_t)b << 4) + h) * 2048 + s) * 64 + d] = f2bf(v);
                } else {
                    outf[(size_t)gm * N + gn] = acc[mi][ni][r] + bias0[gn];
                }
            }
}

// ---------------- causal flash attention (32x32 MFMA, in-register softmax) ----------------
// Each wave: 32 q rows (q = l31), 64-kv tiles. Lane-local softmax (1 shfl_xor).
// P packed in-register via cvt_pk + permlane32_swap (T12). No P LDS.
// grid (16,64): bh=(x&7)*8+(y>>3)  [XCD-grouped], qt=(x>>3)*8+(y&7).
__global__ __launch_bounds__(256, 3)
void attn_fwd(const ushort* __restrict__ Qb, const ushort* __restrict__ Kb,
              const ushort* __restrict__ Vb, ushort* __restrict__ Ab) {
    constexpr int S = 2048;
    // ushorts: K[2][4096] @0, V[2][4096] @8192   (32KB)
    __shared__ ushort lds[16384];

    const int x = blockIdx.x, y = blockIdx.y;
    const int bh = (x & 7) * 8 + (y >> 3);
    const int qt = ((x >> 3) << 3) + (y & 7);
    const int b = bh >> 4, h = bh & 15;
    const ushort* Qp = Qb + (size_t)bh * S * 64;
    const ushort* Kp = Kb + (size_t)bh * S * 64;
    const ushort* Vp = Vb + (size_t)bh * S * 64;

    const int t = threadIdx.x, lane = t & 63, w = t >> 6;
    const int l15 = lane & 15, l31 = lane & 31, hi = lane >> 5, g = lane >> 4;

    // staging offsets (elems within a 64x64 tile)
    int koff[2], voff[2];
#pragma unroll
    for (int i = 0; i < 2; i++) {
        int row = (w * 2 + i) * 8 + (lane >> 3);
        int gg = (lane & 7) ^ ((row ^ (row >> 3)) & 7);
        koff[i] = row * 64 + gg * 8;
    }
#pragma unroll
    for (int it = 0; it < 2; it++) {
        int T = (it * 4 + w) * 64 + lane;
        int kvb = T >> 5, db = (T >> 3) & 3, kvr = (T >> 1) & 3, dh = T & 1;
        voff[it] = (kvb * 4 + kvr) * 64 + db * 16 + dh * 8;
    }
    // V tr-read per-lane base (BYTES): subtile [kv/4][d/16][kv&3][d&15];
    // lane -> subtile(hi, db'=(g&1)) + its own 8-byte row-chunk (l15*8).
    const unsigned vtbase = (unsigned)(uintptr_t)&lds[8192]
                          + (hi << 10) + ((g & 1) << 7) + (l15 << 3);

    auto stage = [&](int phase, int k0) {
#pragma unroll
        for (int i = 0; i < 2; i++)
            gload16(Kp + (size_t)k0 * 64 + koff[i], &lds[(phase << 12) + ((w * 2 + i) << 9)]);
#pragma unroll
        for (int it = 0; it < 2; it++)
            gload16(Vp + (size_t)k0 * 64 + voff[it], &lds[8192 + (phase << 12) + (((it << 2) + w) << 9)]);
    };

    const int fb = qt * 128 + w * 32;   // wave q base
    const int nt = 2 * qt + 2;

    // Q frags (pre-scaled by GEMM): B-frag col=q=l31, k=d
    bf16x8 qf[4];
#pragma unroll
    for (int kc = 0; kc < 4; kc++)
        qf[kc] = *(const bf16x8*)&Qp[(size_t)(fb + l31) * 64 + kc * 16 + hi * 8];

    float m = -3e38f, ls = 0.f;
    f32x16 O0 = {}, O1 = {};

    stage(0, 0);

    for (int tile = 0; tile < nt; tile++) {
        const int phase = tile & 1;
        const int k0 = tile * 64;
        if (tile + 1 < nt) {
            stage(phase ^ 1, (tile + 1) * 64);
            asm volatile("s_waitcnt vmcnt(4)" ::: "memory");
        } else {
            asm volatile("s_waitcnt vmcnt(0)" ::: "memory");
        }
        blockbar();

        if (k0 <= fb + 31) {   // wave-uniform causal skip
            const ushort* Kc = &lds[phase << 12];
            // QK^T swapped: S^T = mfma32(A=K, B=Q); col=q=l31, row=kv
            f32x16 s0 = {}, s1 = {};
            {
                bf16x8 kf[4];
#pragma unroll
                for (int kc = 0; kc < 4; kc++) {
                    int row = l31;
                    int sw = (row ^ (row >> 3)) & 7;
                    kf[kc] = *(const bf16x8*)&Kc[row * 64 + (((kc * 2 + hi) ^ sw) << 3)];
                }
                __builtin_amdgcn_s_setprio(1);
#pragma unroll
                for (int kc = 0; kc < 4; kc++)
                    s0 = __builtin_amdgcn_mfma_f32_32x32x16_bf16(kf[kc], qf[kc], s0, 0, 0, 0);
                __builtin_amdgcn_s_setprio(0);
            }
            {
                bf16x8 kf[4];
#pragma unroll
                for (int kc = 0; kc < 4; kc++) {
                    int row = 32 + l31;
                    int sw = (row ^ (row >> 3)) & 7;
                    kf[kc] = *(const bf16x8*)&Kc[row * 64 + (((kc * 2 + hi) ^ sw) << 3)];
                }
                __builtin_amdgcn_s_setprio(1);
#pragma unroll
                for (int kc = 0; kc < 4; kc++)
                    s1 = __builtin_amdgcn_mfma_f32_32x32x16_bf16(kf[kc], qf[kc], s1, 0, 0, 0);
                __builtin_amdgcn_s_setprio(0);
            }

            // mask (diag tiles only); kv = k0 + kb*32 + (r&3) + 8*(r>>2) + 4*hi
            float pv[32];
            const bool diag = (k0 + 63 > fb);
            const int rel = fb + l31 - k0 - 4 * hi;
#pragma unroll
            for (int r = 0; r < 16; r++) {
                float v0 = s0[r], v1 = s1[r];
                if (diag) {
                    int kvc = (r & 3) + 8 * (r >> 2);
                    if (kvc > rel)      v0 = -1e30f;
                    if (kvc + 32 > rel) v1 = -1e30f;
                }
                pv[r] = v0; pv[16 + r] = v1;
            }
            // lane-local max tree + cross-half
            float mx[16];
#pragma unroll
            for (int i = 0; i < 16; i++) mx[i] = fmaxf(pv[i], pv[i + 16]);
#pragma unroll
            for (int sgap = 8; sgap >= 1; sgap >>= 1)
#pragma unroll
                for (int i = 0; i < sgap; i++) mx[i] = fmaxf(mx[i], mx[i + sgap]);
            float pmax = fmaxf(mx[0], __shfl_xor(mx[0], 32));

            if (!__all(pmax <= m + 8.f)) {   // defer-max (T13)
                float mnew = fmaxf(m, pmax);
                float a = fexp2(m - mnew);
                ls *= a;
                float ar[16];
#pragma unroll
                for (int r = 0; r < 16; r++)
                    ar[r] = __shfl(a, (r & 3) + 8 * (r >> 2) + 4 * hi, 32);
#pragma unroll
                for (int r = 0; r < 16; r++) { O0[r] *= ar[r]; O1[r] *= ar[r]; }
                m = mnew;
            }
            // exp2 + sum tree
#pragma unroll
            for (int i = 0; i < 32; i++) pv[i] = fexp2(pv[i] - m);
            float sm[16];
#pragma unroll
            for (int i = 0; i < 16; i++) sm[i] = pv[i] + pv[i + 16];
#pragma unroll
            for (int sgap = 8; sgap >= 1; sgap >>= 1)
#pragma unroll
                for (int i = 0; i < sgap; i++) sm[i] += sm[i + sgap];
            ls += sm[0] + __shfl_xor(sm[0], 32);

            // T12: pack P to bf16 A-frags in-register (16 cvt_pk + 8 permlane32_swap)
            union PAu { bf16x8 v; unsigned wd[4]; } PA[4];
#pragma unroll
            for (int ks = 0; ks < 4; ks++)
#pragma unroll
                for (int i = 0; i < 2; i++) {
                    unsigned xw = cvtpk(pv[8 * ks + 2 * i], pv[8 * ks + 2 * i + 1]);
                    unsigned yw = cvtpk(pv[8 * ks + 2 * i + 4], pv[8 * ks + 2 * i + 5]);
                    asm("v_permlane32_swap_b32 %0, %1" : "+v"(xw), "+v"(yw));
                    PA[ks].wd[i] = xw; PA[ks].wd[2 + i] = yw;
                }

            // PV: B = V via tr_b16; D col=d, row=q
            const unsigned vtb = vtbase + (phase << 13);
            u32x2 vb[16];
#define TRR(idx, OFFSTR) asm volatile("ds_read_b64_tr_b16 %0, %1 offset:" OFFSTR : "=v"(vb[idx]) : "v"(vtb))
            TRR(0, "0");    TRR(1, "512");  TRR(2, "2048"); TRR(3, "2560");
            TRR(4, "4096"); TRR(5, "4608"); TRR(6, "6144"); TRR(7, "6656");
            TRR(8, "256");  TRR(9, "768");  TRR(10, "2304"); TRR(11, "2816");
            TRR(12, "4352"); TRR(13, "4864"); TRR(14, "6400"); TRR(15, "6912");
#undef TRR
            union FragU { bf16x8 v; u32x2 hh[2]; };
            asm volatile("s_waitcnt lgkmcnt(8)" ::: "memory");
            __builtin_amdgcn_sched_barrier(0);
            __builtin_amdgcn_s_setprio(1);
#pragma unroll
            for (int ks = 0; ks < 4; ks++) {
                FragU f; f.hh[0] = vb[ks * 2]; f.hh[1] = vb[ks * 2 + 1];
                O0 = __builtin_amdgcn_mfma_f32_32x32x16_bf16(PA[ks].v, f.v, O0, 0, 0, 0);
            }
            __builtin_amdgcn_s_setprio(0);
            asm volatile("s_waitcnt lgkmcnt(0)" ::: "memory");
            __builtin_amdgcn_sched_barrier(0);
            __builtin_amdgcn_s_setprio(1);
#pragma unroll
            for (int ks = 0; ks < 4; ks++) {
                FragU f; f.hh[0] = vb[8 + ks * 2]; f.hh[1] = vb[8 + ks * 2 + 1];
                O1 = __builtin_amdgcn_mfma_f32_32x32x16_bf16(PA[ks].v, f.v, O1, 0, 0, 0);
            }
            __builtin_amdgcn_s_setprio(0);
        }
        blockbar();
    }

    // normalize + write merged [B,S,1024]; O row q = (r&3)+8*(r>>2)+4*hi, col d = dblk*32+l31
    float inv[16];
#pragma unroll
    for (int r = 0; r < 16; r++)
        inv[r] = __builtin_amdgcn_rcpf(__shfl(ls, (r & 3) + 8 * (r >> 2) + 4 * hi, 32));
#pragma unroll
    for (int r = 0; r < 16; r++) {
        int q = fb + (r & 3) + 8 * (r >> 2) + 4 * hi;
        size_t base = ((size_t)b * 2048 + q) * 1024 + h * 64;
        Ab[base + l31]      = f2bf(O0[r] * inv[r]);
        Ab[base + 32 + l31] = f2bf(O1[r] * inv[r]);
    }
}

// ---------------- launch ----------------
extern "C" void kernel_launch(void* const* d_in, const int* in_sizes, int n_in,
                              void* d_out, int out_size, void* d_ws, size_t ws_size,
                              hipStream_t stream) {
    const float* query = (const float*)d_in[0];
    const float* Wq = (const float*)d_in[2];
    const float* bq = (const float*)d_in[3];
    const float* Wk = (const float*)d_in[4];
    const float* bk = (const float*)d_in[5];
    const float* Wv = (const float*)d_in[6];
    const float* bv = (const float*)d_in[7];
    const float* Wo = (const float*)d_in[8];
    const float* bo = (const float*)d_in[9];
    float* out = (float*)d_out;

    char* ws = (char*)d_ws;
    const size_t SZ_X = 8192ull * 1024 * 2;
    const size_t SZ_W = 1024ull * 1024 * 2;
    ushort* Xb   = (ushort*)(ws);
    ushort* Wcat = (ushort*)(ws + SZ_X);
    ushort* Wob  = (ushort*)(ws + SZ_X + 3 * SZ_W);
    ushort* QKVb = (ushort*)(ws + SZ_X + 4 * SZ_W);
    ushort* Ab   = (ushort*)(ws + 4 * SZ_X + 4 * SZ_W);

    cvt_f32_bf16<<<1024, 256, 0, stream>>>(query, Xb, 8192 * 1024 / 4);
    cvt_w4<<<1024, 256, 0, stream>>>(Wq, Wk, Wv, Wo, Wcat, Wob);

    gemm_m97<0><<<dim3(3072 / 128, 8192 / 128), 256, 0, stream>>>(
        Xb, Wcat, bq, bk, bv, QKVb, nullptr, 8192, 3072, 1024);

    attn_fwd<<<dim3(16, 64), 256, 0, stream>>>(QKVb, QKVb + 8388608, QKVb + 2 * 8388608, Ab);

    gemm_m97<1><<<dim3(1024 / 128, 8192 / 128), 256, 0, stream>>>(
        Ab, Wob, bo, nullptr, nullptr, nullptr, out, 8192, 1024, 1024);
}

// Round 8
// 175.076 us; speedup vs baseline: 1.2109x; 1.2109x over previous
//
#include <hip/hip_runtime.h>
#include <hip/hip_bf16.h>

typedef __attribute__((ext_vector_type(8))) short bf16x8;
typedef __attribute__((ext_vector_type(4))) float f32x4;
typedef __attribute__((ext_vector_type(16))) float f32x16;
typedef __attribute__((ext_vector_type(2))) unsigned int u32x2;

__device__ __forceinline__ float fexp2(float x) { return __builtin_amdgcn_exp2f(x); }

__device__ __forceinline__ ushort f2bf(float x) {
    union { float f; unsigned u; } c; c.f = x;
    unsigned r = c.u + 0x7fff + ((c.u >> 16) & 1);
    return (ushort)(r >> 16);
}

__device__ __forceinline__ unsigned cvtpk(float lo, float hi) {
    unsigned r;
    asm("v_cvt_pk_bf16_f32 %0, %1, %2" : "=v"(r) : "v"(lo), "v"(hi));
    return r;
}

__device__ __forceinline__ void gload16(const void* g, void* l) {
    __builtin_amdgcn_global_load_lds((const __attribute__((address_space(1))) void*)g,
                                     (__attribute__((address_space(3))) void*)l, 16, 0, 0);
}

__device__ __forceinline__ void blockbar() {
    asm volatile("" ::: "memory");
    __builtin_amdgcn_s_barrier();
    asm volatile("" ::: "memory");
}

// ---------------- f32 -> bf16 converts ----------------
__global__ void cvt_f32_bf16(const float* __restrict__ in, ushort* __restrict__ out, int n4) {
    int i = blockIdx.x * blockDim.x + threadIdx.x;
    int stride = gridDim.x * blockDim.x;
    for (; i < n4; i += stride) {
        float4 v = ((const float4*)in)[i];
        ushort4 o;
        o.x = f2bf(v.x); o.y = f2bf(v.y); o.z = f2bf(v.z); o.w = f2bf(v.w);
        ((ushort4*)out)[i] = o;
    }
}

__global__ void cvt_w4(const float* __restrict__ a, const float* __restrict__ b,
                       const float* __restrict__ c, const float* __restrict__ d,
                       ushort* __restrict__ oq, ushort* __restrict__ ow) {
    const int N4 = 262144;
    int i = blockIdx.x * blockDim.x + threadIdx.x;
    int stride = gridDim.x * blockDim.x;
    for (; i < 4 * N4; i += stride) {
        int sel = i >> 18, local = i & (N4 - 1);
        const float* src = (sel == 0) ? a : (sel == 1) ? b : (sel == 2) ? c : d;
        float4 v = ((const float4*)src)[local];
        ushort4 o;
        o.x = f2bf(v.x); o.y = f2bf(v.y); o.z = f2bf(v.z); o.w = f2bf(v.w);
        if (sel < 3) ((ushort4*)oq)[sel * N4 + local] = o;
        else         ((ushort4*)ow)[local] = o;
    }
}

// ---------------- m97-style bf16 GEMM ----------------
// MODE 0: QKV-cat; Q third pre-scaled by 0.125*log2(e) for exp2-domain attn
template<int MODE>
__global__ __launch_bounds__(256)
void gemm_m97(const ushort* __restrict__ A, const ushort* __restrict__ Bt,
              const float* __restrict__ bias0, const float* __restrict__ bias1,
              const float* __restrict__ bias2,
              ushort* __restrict__ outb, float* __restrict__ outf,
              int M, int N, int K) {
    __shared__ ushort As[128 * 32];
    __shared__ ushort Bs[128 * 32];
    const int t = threadIdx.x, lane = t & 63, w = t >> 6;
    const int wr = w >> 1, wc = w & 1;
    const int l15 = lane & 15, lg = lane >> 4;
    const int nwg = gridDim.x * gridDim.y;
    const int bid = blockIdx.y * gridDim.x + blockIdx.x;
    const int swz = (bid & 7) * (nwg >> 3) + (bid >> 3);
    const int m0 = (swz / gridDim.x) * 128, n0 = (swz % gridDim.x) * 128;
    const int srow = lane >> 2;
    const int sg = (lane & 3) ^ ((lane >> 2) & 3);

    f32x4 acc[4][4] = {};

    for (int k0 = 0; k0 < K; k0 += 32) {
#pragma unroll
        for (int i = 0; i < 2; i++) {
            int c = i * 4 + w;
            const ushort* as = A + (size_t)(m0 + c * 16 + srow) * K + k0 + sg * 8;
            const ushort* bs = Bt + (size_t)(n0 + c * 16 + srow) * K + k0 + sg * 8;
            gload16(as, &As[c * 512]);
            gload16(bs, &Bs[c * 512]);
        }
        __syncthreads();
        bf16x8 af[4], bfr[4];
#pragma unroll
        for (int mi = 0; mi < 4; mi++) {
            int row = wr * 64 + mi * 16 + l15;
            af[mi] = *(const bf16x8*)&As[row * 32 + ((lg ^ (row & 3)) << 3)];
        }
#pragma unroll
        for (int ni = 0; ni < 4; ni++) {
            int row = wc * 64 + ni * 16 + l15;
            bfr[ni] = *(const bf16x8*)&Bs[row * 32 + ((lg ^ (row & 3)) << 3)];
        }
        __builtin_amdgcn_s_setprio(1);
#pragma unroll
        for (int mi = 0; mi < 4; mi++)
#pragma unroll
            for (int ni = 0; ni < 4; ni++)
                acc[mi][ni] = __builtin_amdgcn_mfma_f32_16x16x32_bf16(af[mi], bfr[ni], acc[mi][ni], 0, 0, 0);
        __builtin_amdgcn_s_setprio(0);
        __syncthreads();
    }

#pragma unroll
    for (int mi = 0; mi < 4; mi++)
#pragma unroll
        for (int ni = 0; ni < 4; ni++)
#pragma unroll
            for (int r = 0; r < 4; r++) {
                int gm = m0 + wr * 64 + mi * 16 + lg * 4 + r;
                int gn = n0 + wc * 64 + ni * 16 + l15;
                if (MODE == 0) {
                    const float* bp = (gn < 1024) ? bias0 : ((gn < 2048) ? bias1 : bias2);
                    float v = acc[mi][ni][r] + bp[gn & 1023];
                    if (gn < 1024) v *= 0.18033688011f;  // 0.125 * log2(e)
                    int proj = gn >> 10, nn = gn & 1023;
                    int h = nn >> 6, d = nn & 63;
                    int b = gm >> 11, s = gm & 2047;
                    outb[(size_t)proj * 8388608 + ((((size_t)b << 4) + h) * 2048 + s) * 64 + d] = f2bf(v);
                } else {
                    outf[(size_t)gm * N + gn] = acc[mi][ni][r] + bias0[gn];
                }
            }
}

// ---------------- causal flash attention (32x32 MFMA, in-register softmax) ----------------
// Each wave: 32 q rows (q = l31), 64-kv tiles. Lane-local softmax (1 shfl_xor).
// P packed in-register via cvt_pk + permlane32_swap (T12). No P LDS.
// 1D grid 1024, LPT order: qt = 15 - (bid>>6) (longest blocks first), bh = bid&63
// (XCD ~ bid%8 = bh%8, so each head stays on one XCD's L2).
__global__ __launch_bounds__(256, 3)
void attn_fwd(const ushort* __restrict__ Qb, const ushort* __restrict__ Kb,
              const ushort* __restrict__ Vb, ushort* __restrict__ Ab) {
    constexpr int S = 2048;
    // ushorts: K[2][4096] @0, V[2][4096] @8192   (32KB)
    __shared__ ushort lds[16384];

    const int bid = blockIdx.x;
    const int qt = 15 - (bid >> 6);
    const int bh = bid & 63;
    const int b = bh >> 4, h = bh & 15;
    const ushort* Qp = Qb + (size_t)bh * S * 64;
    const ushort* Kp = Kb + (size_t)bh * S * 64;
    const ushort* Vp = Vb + (size_t)bh * S * 64;

    const int t = threadIdx.x, lane = t & 63, w = t >> 6;
    const int l15 = lane & 15, l31 = lane & 31, hi = lane >> 5, g = lane >> 4;

    // staging offsets (elems within a 64x64 tile)
    int koff[2], voff[2];
#pragma unroll
    for (int i = 0; i < 2; i++) {
        int row = (w * 2 + i) * 8 + (lane >> 3);
        int gg = (lane & 7) ^ ((row ^ (row >> 3)) & 7);
        koff[i] = row * 64 + gg * 8;
    }
#pragma unroll
    for (int it = 0; it < 2; it++) {
        int T = (it * 4 + w) * 64 + lane;
        int kvb = T >> 5, db = (T >> 3) & 3, kvr = (T >> 1) & 3, dh = T & 1;
        voff[it] = (kvb * 4 + kvr) * 64 + db * 16 + dh * 8;
    }
    // V tr-read per-lane base (BYTES): subtile [kv/4][d/16][kv&3][d&15];
    // lane -> subtile(hi, db'=(g&1)) + its own 8-byte row-chunk (l15*8).
    const unsigned vtbase = (unsigned)(uintptr_t)&lds[8192]
                          + (hi << 10) + ((g & 1) << 7) + (l15 << 3);

    auto stage = [&](int phase, int k0) {
#pragma unroll
        for (int i = 0; i < 2; i++)
            gload16(Kp + (size_t)k0 * 64 + koff[i], &lds[(phase << 12) + ((w * 2 + i) << 9)]);
#pragma unroll
        for (int it = 0; it < 2; it++)
            gload16(Vp + (size_t)k0 * 64 + voff[it], &lds[8192 + (phase << 12) + (((it << 2) + w) << 9)]);
    };

    const int fb = qt * 128 + w * 32;   // wave q base
    const int nt = 2 * qt + 2;

    // Q frags (pre-scaled by GEMM): B-frag col=q=l31, k=d
    bf16x8 qf[4];
#pragma unroll
    for (int kc = 0; kc < 4; kc++)
        qf[kc] = *(const bf16x8*)&Qp[(size_t)(fb + l31) * 64 + kc * 16 + hi * 8];

    float m = -3e38f, ls = 0.f;
    f32x16 O0 = {}, O1 = {};

    stage(0, 0);

    for (int tile = 0; tile < nt; tile++) {
        const int phase = tile & 1;
        const int k0 = tile * 64;
        if (tile + 1 < nt) {
            stage(phase ^ 1, (tile + 1) * 64);
            asm volatile("s_waitcnt vmcnt(4)" ::: "memory");
        } else {
            asm volatile("s_waitcnt vmcnt(0)" ::: "memory");
        }
        blockbar();

        if (k0 <= fb + 31) {   // wave-uniform causal skip
            const ushort* Kc = &lds[phase << 12];
            // QK^T swapped: S^T = mfma32(A=K, B=Q); col=q=l31, row=kv
            f32x16 s0 = {}, s1 = {};
            {
                bf16x8 kf[4];
#pragma unroll
                for (int kc = 0; kc < 4; kc++) {
                    int row = l31;
                    int sw = (row ^ (row >> 3)) & 7;
                    kf[kc] = *(const bf16x8*)&Kc[row * 64 + (((kc * 2 + hi) ^ sw) << 3)];
                }
                __builtin_amdgcn_s_setprio(1);
#pragma unroll
                for (int kc = 0; kc < 4; kc++)
                    s0 = __builtin_amdgcn_mfma_f32_32x32x16_bf16(kf[kc], qf[kc], s0, 0, 0, 0);
                __builtin_amdgcn_s_setprio(0);
            }
            {
                bf16x8 kf[4];
#pragma unroll
                for (int kc = 0; kc < 4; kc++) {
                    int row = 32 + l31;
                    int sw = (row ^ (row >> 3)) & 7;
                    kf[kc] = *(const bf16x8*)&Kc[row * 64 + (((kc * 2 + hi) ^ sw) << 3)];
                }
                __builtin_amdgcn_s_setprio(1);
#pragma unroll
                for (int kc = 0; kc < 4; kc++)
                    s1 = __builtin_amdgcn_mfma_f32_32x32x16_bf16(kf[kc], qf[kc], s1, 0, 0, 0);
                __builtin_amdgcn_s_setprio(0);
            }

            // mask (diag tiles only); kv = k0 + kb*32 + (r&3) + 8*(r>>2) + 4*hi
            float pv[32];
            const bool diag = (k0 + 63 > fb);
            const int rel = fb + l31 - k0 - 4 * hi;
#pragma unroll
            for (int r = 0; r < 16; r++) {
                float v0 = s0[r], v1 = s1[r];
                if (diag) {
                    int kvc = (r & 3) + 8 * (r >> 2);
                    if (kvc > rel)      v0 = -1e30f;
                    if (kvc + 32 > rel) v1 = -1e30f;
                }
                pv[r] = v0; pv[16 + r] = v1;
            }
            // lane-local max tree + cross-half
            float mx[16];
#pragma unroll
            for (int i = 0; i < 16; i++) mx[i] = fmaxf(pv[i], pv[i + 16]);
#pragma unroll
            for (int sgap = 8; sgap >= 1; sgap >>= 1)
#pragma unroll
                for (int i = 0; i < sgap; i++) mx[i] = fmaxf(mx[i], mx[i + sgap]);
            float pmax = fmaxf(mx[0], __shfl_xor(mx[0], 32));

            if (!__all(pmax <= m + 8.f)) {   // defer-max (T13)
                float mnew = fmaxf(m, pmax);
                float a = fexp2(m - mnew);
                ls *= a;
                float ar[16];
#pragma unroll
                for (int r = 0; r < 16; r++)
                    ar[r] = __shfl(a, (r & 3) + 8 * (r >> 2) + 4 * hi, 32);
#pragma unroll
                for (int r = 0; r < 16; r++) { O0[r] *= ar[r]; O1[r] *= ar[r]; }
                m = mnew;
            }
            // exp2 + sum tree
#pragma unroll
            for (int i = 0; i < 32; i++) pv[i] = fexp2(pv[i] - m);
            float sm[16];
#pragma unroll
            for (int i = 0; i < 16; i++) sm[i] = pv[i] + pv[i + 16];
#pragma unroll
            for (int sgap = 8; sgap >= 1; sgap >>= 1)
#pragma unroll
                for (int i = 0; i < sgap; i++) sm[i] += sm[i + sgap];
            ls += sm[0] + __shfl_xor(sm[0], 32);

            // T12: pack P to bf16 A-frags in-register (16 cvt_pk + 8 permlane32_swap)
            union PAu { bf16x8 v; unsigned wd[4]; } PA[4];
#pragma unroll
            for (int ks = 0; ks < 4; ks++)
#pragma unroll
                for (int i = 0; i < 2; i++) {
                    unsigned xw = cvtpk(pv[8 * ks + 2 * i], pv[8 * ks + 2 * i + 1]);
                    unsigned yw = cvtpk(pv[8 * ks + 2 * i + 4], pv[8 * ks + 2 * i + 5]);
                    asm("v_permlane32_swap_b32 %0, %1" : "+v"(xw), "+v"(yw));
                    PA[ks].wd[i] = xw; PA[ks].wd[2 + i] = yw;
                }

            // PV: B = V via tr_b16; D col=d, row=q
            const unsigned vtb = vtbase + (phase << 13);
            u32x2 vb[16];
#define TRR(idx, OFFSTR) asm volatile("ds_read_b64_tr_b16 %0, %1 offset:" OFFSTR : "=v"(vb[idx]) : "v"(vtb))
            TRR(0, "0");    TRR(1, "512");  TRR(2, "2048"); TRR(3, "2560");
            TRR(4, "4096"); TRR(5, "4608"); TRR(6, "6144"); TRR(7, "6656");
            TRR(8, "256");  TRR(9, "768");  TRR(10, "2304"); TRR(11, "2816");
            TRR(12, "4352"); TRR(13, "4864"); TRR(14, "6400"); TRR(15, "6912");
#undef TRR
            union FragU { bf16x8 v; u32x2 hh[2]; };
            asm volatile("s_waitcnt lgkmcnt(8)" ::: "memory");
            __builtin_amdgcn_sched_barrier(0);
            __builtin_amdgcn_s_setprio(1);
#pragma unroll
            for (int ks = 0; ks < 4; ks++) {
                FragU f; f.hh[0] = vb[ks * 2]; f.hh[1] = vb[ks * 2 + 1];
                O0 = __builtin_amdgcn_mfma_f32_32x32x16_bf16(PA[ks].v, f.v, O0, 0, 0, 0);
            }
            __builtin_amdgcn_s_setprio(0);
            asm volatile("s_waitcnt lgkmcnt(0)" ::: "memory");
            __builtin_amdgcn_sched_barrier(0);
            __builtin_amdgcn_s_setprio(1);
#pragma unroll
            for (int ks = 0; ks < 4; ks++) {
                FragU f; f.hh[0] = vb[8 + ks * 2]; f.hh[1] = vb[8 + ks * 2 + 1];
                O1 = __builtin_amdgcn_mfma_f32_32x32x16_bf16(PA[ks].v, f.v, O1, 0, 0, 0);
            }
            __builtin_amdgcn_s_setprio(0);
        }
        blockbar();
    }

    // normalize + write merged [B,S,1024]; O row q = (r&3)+8*(r>>2)+4*hi, col d = dblk*32+l31
    float inv[16];
#pragma unroll
    for (int r = 0; r < 16; r++)
        inv[r] = __builtin_amdgcn_rcpf(__shfl(ls, (r & 3) + 8 * (r >> 2) + 4 * hi, 32));
#pragma unroll
    for (int r = 0; r < 16; r++) {
        int q = fb + (r & 3) + 8 * (r >> 2) + 4 * hi;
        size_t base = ((size_t)b * 2048 + q) * 1024 + h * 64;
        Ab[base + l31]      = f2bf(O0[r] * inv[r]);
        Ab[base + 32 + l31] = f2bf(O1[r] * inv[r]);
    }
}

// ---------------- launch ----------------
extern "C" void kernel_launch(void* const* d_in, const int* in_sizes, int n_in,
                              void* d_out, int out_size, void* d_ws, size_t ws_size,
                              hipStream_t stream) {
    const float* query = (const float*)d_in[0];
    const float* Wq = (const float*)d_in[2];
    const float* bq = (const float*)d_in[3];
    const float* Wk = (const float*)d_in[4];
    const float* bk = (const float*)d_in[5];
    const float* Wv = (const float*)d_in[6];
    const float* bv = (const float*)d_in[7];
    const float* Wo = (const float*)d_in[8];
    const float* bo = (const float*)d_in[9];
    float* out = (float*)d_out;

    char* ws = (char*)d_ws;
    const size_t SZ_X = 8192ull * 1024 * 2;
    const size_t SZ_W = 1024ull * 1024 * 2;
    ushort* Xb   = (ushort*)(ws);
    ushort* Wcat = (ushort*)(ws + SZ_X);
    ushort* Wob  = (ushort*)(ws + SZ_X + 3 * SZ_W);
    ushort* QKVb = (ushort*)(ws + SZ_X + 4 * SZ_W);
    ushort* Ab   = (ushort*)(ws + 4 * SZ_X + 4 * SZ_W);

    cvt_f32_bf16<<<1024, 256, 0, stream>>>(query, Xb, 8192 * 1024 / 4);
    cvt_w4<<<1024, 256, 0, stream>>>(Wq, Wk, Wv, Wo, Wcat, Wob);

    gemm_m97<0><<<dim3(3072 / 128, 8192 / 128), 256, 0, stream>>>(
        Xb, Wcat, bq, bk, bv, QKVb, nullptr, 8192, 3072, 1024);

    attn_fwd<<<1024, 256, 0, stream>>>(QKVb, QKVb + 8388608, QKVb + 2 * 8388608, Ab);

    gemm_m97<1><<<dim3(1024 / 128, 8192 / 128), 256, 0, stream>>>(
        Ab, Wob, bo, nullptr, nullptr, nullptr, out, 8192, 1024, 1024);
}

// Round 9
// 174.608 us; speedup vs baseline: 1.2141x; 1.0027x over previous
//
#include <hip/hip_runtime.h>
#include <hip/hip_bf16.h>

typedef __attribute__((ext_vector_type(8))) short bf16x8;
typedef __attribute__((ext_vector_type(4))) float f32x4;
typedef __attribute__((ext_vector_type(16))) float f32x16;
typedef __attribute__((ext_vector_type(2))) unsigned int u32x2;

__device__ __forceinline__ float fexp2(float x) { return __builtin_amdgcn_exp2f(x); }

__device__ __forceinline__ ushort f2bf(float x) {
    union { float f; unsigned u; } c; c.f = x;
    unsigned r = c.u + 0x7fff + ((c.u >> 16) & 1);
    return (ushort)(r >> 16);
}

__device__ __forceinline__ unsigned cvtpk(float lo, float hi) {
    unsigned r;
    asm("v_cvt_pk_bf16_f32 %0, %1, %2" : "=v"(r) : "v"(lo), "v"(hi));
    return r;
}

__device__ __forceinline__ void gload16(const void* g, void* l) {
    __builtin_amdgcn_global_load_lds((const __attribute__((address_space(1))) void*)g,
                                     (__attribute__((address_space(3))) void*)l, 16, 0, 0);
}

__device__ __forceinline__ void blockbar() {
    asm volatile("" ::: "memory");
    __builtin_amdgcn_s_barrier();
    asm volatile("" ::: "memory");
}

template<int N> __device__ __forceinline__ void vmwait() {
    if constexpr (N == 9)      asm volatile("s_waitcnt vmcnt(9)" ::: "memory");
    else if constexpr (N == 6) asm volatile("s_waitcnt vmcnt(6)" ::: "memory");
    else if constexpr (N == 3) asm volatile("s_waitcnt vmcnt(3)" ::: "memory");
    else                       asm volatile("s_waitcnt vmcnt(0)" ::: "memory");
}

// ---------------- f32 -> bf16 converts ----------------
__global__ void cvt_f32_bf16(const float* __restrict__ in, ushort* __restrict__ out, int n4) {
    int i = blockIdx.x * blockDim.x + threadIdx.x;
    int stride = gridDim.x * blockDim.x;
    for (; i < n4; i += stride) {
        float4 v = ((const float4*)in)[i];
        ushort4 o;
        o.x = f2bf(v.x); o.y = f2bf(v.y); o.z = f2bf(v.z); o.w = f2bf(v.w);
        ((ushort4*)out)[i] = o;
    }
}

__global__ void cvt_w4(const float* __restrict__ a, const float* __restrict__ b,
                       const float* __restrict__ c, const float* __restrict__ d,
                       ushort* __restrict__ oq, ushort* __restrict__ ow) {
    const int N4 = 262144;
    int i = blockIdx.x * blockDim.x + threadIdx.x;
    int stride = gridDim.x * blockDim.x;
    for (; i < 4 * N4; i += stride) {
        int sel = i >> 18, local = i & (N4 - 1);
        const float* src = (sel == 0) ? a : (sel == 1) ? b : (sel == 2) ? c : d;
        float4 v = ((const float4*)src)[local];
        ushort4 o;
        o.x = f2bf(v.x); o.y = f2bf(v.y); o.z = f2bf(v.z); o.w = f2bf(v.w);
        if (sel < 3) ((ushort4*)oq)[sel * N4 + local] = o;
        else         ((ushort4*)ow)[local] = o;
    }
}

// ---------------- pipelined bf16 GEMM: C[M,N] = A[M,K] @ Bt[N,K]^T + bias ----------------
// 256x128 tile, 512 thr (8 waves 4Mx2N, per-wave C 64x64), 4-stage K=32 pipeline,
// counted vmcnt(9), conflict-free LDS (blk ^ ((row>>1)&3)), setprio MFMA clusters.
// MODE 0: QKV-cat bf16 out (Q pre-scaled); MODE 1: f32 out + bias0.
template<int MODE>
__global__ __launch_bounds__(512, 2)
void gemm_8p(const ushort* __restrict__ A, const ushort* __restrict__ Bt,
             const float* __restrict__ bias0, const float* __restrict__ bias1,
             const float* __restrict__ bias2,
             ushort* __restrict__ outb, float* __restrict__ outf,
             int M, int N, int K) {
    __shared__ ushort lds[49152];   // 4 stages x (A 8192 + B 4096) ushorts = 96KB
    const int t = threadIdx.x, lane = t & 63, w = t >> 6;
    const int wm = w >> 1, wn = w & 1;
    const int l15 = lane & 15, lg = lane >> 4;
    const int asw = (l15 >> 1) & 3;

    const int nbx = N >> 7;
    const int nwg = nbx * (M >> 8);
    const int bid = blockIdx.y * nbx + blockIdx.x;
    const int swz = (bid & 7) * (nwg >> 3) + (bid >> 3);
    const int m0 = (swz / nbx) * 256, n0 = (swz % nbx) * 128;

    // staging: per stage, wave w owns A chunks {w, 8+w} and B chunk {w} (1KB each).
    const int srow = lane >> 2;
    const int sblk = (lane & 3) ^ ((lane >> 3) & 3);
    const ushort* Asrc0 = A + (size_t)(m0 + 16 * w + srow) * K + sblk * 8;
    const ushort* Asrc1 = A + (size_t)(m0 + 128 + 16 * w + srow) * K + sblk * 8;
    const ushort* Bsrc  = Bt + (size_t)(n0 + 16 * w + srow) * K + sblk * 8;
    ushort* ldsA0 = &lds[w * 512];
    ushort* ldsA1 = &lds[(8 + w) * 512];
    ushort* ldsB  = &lds[8192 + w * 512];

#define STAGE(ST, KT) { \
    gload16(Asrc0 + (KT) * 32, ldsA0 + (ST) * 12288); \
    gload16(Asrc1 + (KT) * 32, ldsA1 + (ST) * 12288); \
    gload16(Bsrc  + (KT) * 32, ldsB  + (ST) * 12288); }

    const int abase = (wm * 64 + l15) * 32 + ((lg ^ asw) << 3);
    const int bbase = 8192 + (wn * 64 + l15) * 32 + ((lg ^ asw) << 3);

    f32x4 acc[4][4] = {};
    const int NT = K >> 5;

    STAGE(0, 0); STAGE(1, 1); STAGE(2, 2);

    for (int kt = 0; kt < NT; ++kt) {
        if (kt + 3 < NT) STAGE((kt + 3) & 3, kt + 3);
        const int ahead = NT - 1 - kt;
        if (ahead >= 3) vmwait<9>();
        else if (ahead == 2) vmwait<6>();
        else if (ahead == 1) vmwait<3>();
        else vmwait<0>();
        blockbar();

        const ushort* sa = lds + (kt & 3) * 12288 + abase;
        const ushort* sb = lds + (kt & 3) * 12288 + bbase;
        bf16x8 af[4], bfr[4];
#pragma unroll
        for (int mi = 0; mi < 4; mi++) af[mi] = *(const bf16x8*)(sa + mi * 512);
#pragma unroll
        for (int ni = 0; ni < 4; ni++) bfr[ni] = *(const bf16x8*)(sb + ni * 512);

        __builtin_amdgcn_s_setprio(1);
#pragma unroll
        for (int mi = 0; mi < 4; mi++)
#pragma unroll
            for (int ni = 0; ni < 4; ni++)
                acc[mi][ni] = __builtin_amdgcn_mfma_f32_16x16x32_bf16(af[mi], bfr[ni], acc[mi][ni], 0, 0, 0);
        __builtin_amdgcn_s_setprio(0);
        blockbar();
    }
#undef STAGE

#pragma unroll
    for (int mi = 0; mi < 4; mi++)
#pragma unroll
        for (int ni = 0; ni < 4; ni++)
#pragma unroll
            for (int r = 0; r < 4; r++) {
                int gm = m0 + wm * 64 + mi * 16 + lg * 4 + r;
                int gn = n0 + wn * 64 + ni * 16 + l15;
                if (MODE == 0) {
                    const float* bp = (gn < 1024) ? bias0 : ((gn < 2048) ? bias1 : bias2);
                    float v = acc[mi][ni][r] + bp[gn & 1023];
                    if (gn < 1024) v *= 0.18033688011f;  // 0.125 * log2(e)
                    int proj = gn >> 10, nn = gn & 1023;
                    int h = nn >> 6, d = nn & 63;
                    int b = gm >> 11, s = gm & 2047;
                    outb[(size_t)proj * 8388608 + ((((size_t)b << 4) + h) * 2048 + s) * 64 + d] = f2bf(v);
                } else {
                    outf[(size_t)gm * N + gn] = acc[mi][ni][r] + bias0[gn];
                }
            }
}

// ---------------- causal flash attention (32x32 MFMA, in-register softmax) ----------------
// Each wave: 32 q rows (q = l31), 64-kv tiles. Lane-local softmax (1 shfl_xor).
// P packed in-register via cvt_pk + permlane32_swap (T12). No P LDS.
// 1D grid 1024, LPT order: qt = 15 - (bid>>6) (longest blocks first), bh = bid&63.
__global__ __launch_bounds__(256, 3)
void attn_fwd(const ushort* __restrict__ Qb, const ushort* __restrict__ Kb,
              const ushort* __restrict__ Vb, ushort* __restrict__ Ab) {
    constexpr int S = 2048;
    __shared__ ushort lds[16384];

    const int bid = blockIdx.x;
    const int qt = 15 - (bid >> 6);
    const int bh = bid & 63;
    const int b = bh >> 4, h = bh & 15;
    const ushort* Qp = Qb + (size_t)bh * S * 64;
    const ushort* Kp = Kb + (size_t)bh * S * 64;
    const ushort* Vp = Vb + (size_t)bh * S * 64;

    const int t = threadIdx.x, lane = t & 63, w = t >> 6;
    const int l15 = lane & 15, l31 = lane & 31, hi = lane >> 5, g = lane >> 4;

    int koff[2], voff[2];
#pragma unroll
    for (int i = 0; i < 2; i++) {
        int row = (w * 2 + i) * 8 + (lane >> 3);
        int gg = (lane & 7) ^ ((row ^ (row >> 3)) & 7);
        koff[i] = row * 64 + gg * 8;
    }
#pragma unroll
    for (int it = 0; it < 2; it++) {
        int T = (it * 4 + w) * 64 + lane;
        int kvb = T >> 5, db = (T >> 3) & 3, kvr = (T >> 1) & 3, dh = T & 1;
        voff[it] = (kvb * 4 + kvr) * 64 + db * 16 + dh * 8;
    }
    const unsigned vtbase = (unsigned)(uintptr_t)&lds[8192]
                          + (hi << 10) + ((g & 1) << 7) + (l15 << 3);

    auto stage = [&](int phase, int k0) {
#pragma unroll
        for (int i = 0; i < 2; i++)
            gload16(Kp + (size_t)k0 * 64 + koff[i], &lds[(phase << 12) + ((w * 2 + i) << 9)]);
#pragma unroll
        for (int it = 0; it < 2; it++)
            gload16(Vp + (size_t)k0 * 64 + voff[it], &lds[8192 + (phase << 12) + (((it << 2) + w) << 9)]);
    };

    const int fb = qt * 128 + w * 32;
    const int nt = 2 * qt + 2;

    bf16x8 qf[4];
#pragma unroll
    for (int kc = 0; kc < 4; kc++)
        qf[kc] = *(const bf16x8*)&Qp[(size_t)(fb + l31) * 64 + kc * 16 + hi * 8];

    float m = -3e38f, ls = 0.f;
    f32x16 O0 = {}, O1 = {};

    stage(0, 0);

    for (int tile = 0; tile < nt; tile++) {
        const int phase = tile & 1;
        const int k0 = tile * 64;
        if (tile + 1 < nt) {
            stage(phase ^ 1, (tile + 1) * 64);
            asm volatile("s_waitcnt vmcnt(4)" ::: "memory");
        } else {
            asm volatile("s_waitcnt vmcnt(0)" ::: "memory");
        }
        blockbar();

        if (k0 <= fb + 31) {
            const ushort* Kc = &lds[phase << 12];
            f32x16 s0 = {}, s1 = {};
            {
                bf16x8 kf[4];
#pragma unroll
                for (int kc = 0; kc < 4; kc++) {
                    int row = l31;
                    int sw = (row ^ (row >> 3)) & 7;
                    kf[kc] = *(const bf16x8*)&Kc[row * 64 + (((kc * 2 + hi) ^ sw) << 3)];
                }
                __builtin_amdgcn_s_setprio(1);
#pragma unroll
                for (int kc = 0; kc < 4; kc++)
                    s0 = __builtin_amdgcn_mfma_f32_32x32x16_bf16(kf[kc], qf[kc], s0, 0, 0, 0);
                __builtin_amdgcn_s_setprio(0);
            }
            {
                bf16x8 kf[4];
#pragma unroll
                for (int kc = 0; kc < 4; kc++) {
                    int row = 32 + l31;
                    int sw = (row ^ (row >> 3)) & 7;
                    kf[kc] = *(const bf16x8*)&Kc[row * 64 + (((kc * 2 + hi) ^ sw) << 3)];
                }
                __builtin_amdgcn_s_setprio(1);
#pragma unroll
                for (int kc = 0; kc < 4; kc++)
                    s1 = __builtin_amdgcn_mfma_f32_32x32x16_bf16(kf[kc], qf[kc], s1, 0, 0, 0);
                __builtin_amdgcn_s_setprio(0);
            }

            float pv[32];
            const bool diag = (k0 + 63 > fb);
            const int rel = fb + l31 - k0 - 4 * hi;
#pragma unroll
            for (int r = 0; r < 16; r++) {
                float v0 = s0[r], v1 = s1[r];
                if (diag) {
                    int kvc = (r & 3) + 8 * (r >> 2);
                    if (kvc > rel)      v0 = -1e30f;
                    if (kvc + 32 > rel) v1 = -1e30f;
                }
                pv[r] = v0; pv[16 + r] = v1;
            }
            float mx[16];
#pragma unroll
            for (int i = 0; i < 16; i++) mx[i] = fmaxf(pv[i], pv[i + 16]);
#pragma unroll
            for (int sgap = 8; sgap >= 1; sgap >>= 1)
#pragma unroll
                for (int i = 0; i < sgap; i++) mx[i] = fmaxf(mx[i], mx[i + sgap]);
            float pmax = fmaxf(mx[0], __shfl_xor(mx[0], 32));

            if (!__all(pmax <= m + 8.f)) {
                float mnew = fmaxf(m, pmax);
                float a = fexp2(m - mnew);
                ls *= a;
                float ar[16];
#pragma unroll
                for (int r = 0; r < 16; r++)
                    ar[r] = __shfl(a, (r & 3) + 8 * (r >> 2) + 4 * hi, 32);
#pragma unroll
                for (int r = 0; r < 16; r++) { O0[r] *= ar[r]; O1[r] *= ar[r]; }
                m = mnew;
            }
#pragma unroll
            for (int i = 0; i < 32; i++) pv[i] = fexp2(pv[i] - m);
            float sm[16];
#pragma unroll
            for (int i = 0; i < 16; i++) sm[i] = pv[i] + pv[i + 16];
#pragma unroll
            for (int sgap = 8; sgap >= 1; sgap >>= 1)
#pragma unroll
                for (int i = 0; i < sgap; i++) sm[i] += sm[i + sgap];
            ls += sm[0] + __shfl_xor(sm[0], 32);

            union PAu { bf16x8 v; unsigned wd[4]; } PA[4];
#pragma unroll
            for (int ks = 0; ks < 4; ks++)
#pragma unroll
                for (int i = 0; i < 2; i++) {
                    unsigned xw = cvtpk(pv[8 * ks + 2 * i], pv[8 * ks + 2 * i + 1]);
                    unsigned yw = cvtpk(pv[8 * ks + 2 * i + 4], pv[8 * ks + 2 * i + 5]);
                    asm("v_permlane32_swap_b32 %0, %1" : "+v"(xw), "+v"(yw));
                    PA[ks].wd[i] = xw; PA[ks].wd[2 + i] = yw;
                }

            const unsigned vtb = vtbase + (phase << 13);
            u32x2 vb[16];
#define TRR(idx, OFFSTR) asm volatile("ds_read_b64_tr_b16 %0, %1 offset:" OFFSTR : "=v"(vb[idx]) : "v"(vtb))
            TRR(0, "0");    TRR(1, "512");  TRR(2, "2048"); TRR(3, "2560");
            TRR(4, "4096"); TRR(5, "4608"); TRR(6, "6144"); TRR(7, "6656");
            TRR(8, "256");  TRR(9, "768");  TRR(10, "2304"); TRR(11, "2816");
            TRR(12, "4352"); TRR(13, "4864"); TRR(14, "6400"); TRR(15, "6912");
#undef TRR
            union FragU { bf16x8 v; u32x2 hh[2]; };
            asm volatile("s_waitcnt lgkmcnt(8)" ::: "memory");
            __builtin_amdgcn_sched_barrier(0);
            __builtin_amdgcn_s_setprio(1);
#pragma unroll
            for (int ks = 0; ks < 4; ks++) {
                FragU f; f.hh[0] = vb[ks * 2]; f.hh[1] = vb[ks * 2 + 1];
                O0 = __builtin_amdgcn_mfma_f32_32x32x16_bf16(PA[ks].v, f.v, O0, 0, 0, 0);
            }
            __builtin_amdgcn_s_setprio(0);
            asm volatile("s_waitcnt lgkmcnt(0)" ::: "memory");
            __builtin_amdgcn_sched_barrier(0);
            __builtin_amdgcn_s_setprio(1);
#pragma unroll
            for (int ks = 0; ks < 4; ks++) {
                FragU f; f.hh[0] = vb[8 + ks * 2]; f.hh[1] = vb[8 + ks * 2 + 1];
                O1 = __builtin_amdgcn_mfma_f32_32x32x16_bf16(PA[ks].v, f.v, O1, 0, 0, 0);
            }
            __builtin_amdgcn_s_setprio(0);
        }
        blockbar();
    }

    float inv[16];
#pragma unroll
    for (int r = 0; r < 16; r++)
        inv[r] = __builtin_amdgcn_rcpf(__shfl(ls, (r & 3) + 8 * (r >> 2) + 4 * hi, 32));
#pragma unroll
    for (int r = 0; r < 16; r++) {
        int q = fb + (r & 3) + 8 * (r >> 2) + 4 * hi;
        size_t base = ((size_t)b * 2048 + q) * 1024 + h * 64;
        Ab[base + l31]      = f2bf(O0[r] * inv[r]);
        Ab[base + 32 + l31] = f2bf(O1[r] * inv[r]);
    }
}

// ---------------- launch ----------------
extern "C" void kernel_launch(void* const* d_in, const int* in_sizes, int n_in,
                              void* d_out, int out_size, void* d_ws, size_t ws_size,
                              hipStream_t stream) {
    const float* query = (const float*)d_in[0];
    const float* Wq = (const float*)d_in[2];
    const float* bq = (const float*)d_in[3];
    const float* Wk = (const float*)d_in[4];
    const float* bk = (const float*)d_in[5];
    const float* Wv = (const float*)d_in[6];
    const float* bv = (const float*)d_in[7];
    const float* Wo = (const float*)d_in[8];
    const float* bo = (const float*)d_in[9];
    float* out = (float*)d_out;

    char* ws = (char*)d_ws;
    const size_t SZ_X = 8192ull * 1024 * 2;
    const size_t SZ_W = 1024ull * 1024 * 2;
    ushort* Xb   = (ushort*)(ws);
    ushort* Wcat = (ushort*)(ws + SZ_X);
    ushort* Wob  = (ushort*)(ws + SZ_X + 3 * SZ_W);
    ushort* QKVb = (ushort*)(ws + SZ_X + 4 * SZ_W);
    ushort* Ab   = (ushort*)(ws + 4 * SZ_X + 4 * SZ_W);

    cvt_f32_bf16<<<1024, 256, 0, stream>>>(query, Xb, 8192 * 1024 / 4);
    cvt_w4<<<1024, 256, 0, stream>>>(Wq, Wk, Wv, Wo, Wcat, Wob);

    gemm_8p<0><<<dim3(3072 / 128, 8192 / 256), 512, 0, stream>>>(
        Xb, Wcat, bq, bk, bv, QKVb, nullptr, 8192, 3072, 1024);

    attn_fwd<<<1024, 256, 0, stream>>>(QKVb, QKVb + 8388608, QKVb + 2 * 8388608, Ab);

    gemm_8p<1><<<dim3(1024 / 128, 8192 / 256), 512, 0, stream>>>(
        Ab, Wob, bo, nullptr, nullptr, nullptr, out, 8192, 1024, 1024);
}

// Round 10
// 164.795 us; speedup vs baseline: 1.2864x; 1.0595x over previous
//
#include <hip/hip_runtime.h>
#include <hip/hip_bf16.h>

typedef __attribute__((ext_vector_type(8))) short bf16x8;
typedef __attribute__((ext_vector_type(4))) float f32x4;
typedef __attribute__((ext_vector_type(16))) float f32x16;
typedef __attribute__((ext_vector_type(2))) unsigned int u32x2;

__device__ __forceinline__ float fexp2(float x) { return __builtin_amdgcn_exp2f(x); }

__device__ __forceinline__ ushort f2bf(float x) {
    union { float f; unsigned u; } c; c.f = x;
    unsigned r = c.u + 0x7fff + ((c.u >> 16) & 1);
    return (ushort)(r >> 16);
}

__device__ __forceinline__ unsigned cvtpk(float lo, float hi) {
    unsigned r;
    asm("v_cvt_pk_bf16_f32 %0, %1, %2" : "=v"(r) : "v"(lo), "v"(hi));
    return r;
}

__device__ __forceinline__ void gload16(const void* g, void* l) {
    __builtin_amdgcn_global_load_lds((const __attribute__((address_space(1))) void*)g,
                                     (__attribute__((address_space(3))) void*)l, 16, 0, 0);
}

__device__ __forceinline__ void blockbar() {
    asm volatile("" ::: "memory");
    __builtin_amdgcn_s_barrier();
    asm volatile("" ::: "memory");
}

// ---------------- f32 -> bf16 converts ----------------
__global__ void cvt_f32_bf16(const float* __restrict__ in, ushort* __restrict__ out, int n4) {
    int i = blockIdx.x * blockDim.x + threadIdx.x;
    int stride = gridDim.x * blockDim.x;
    for (; i < n4; i += stride) {
        float4 v = ((const float4*)in)[i];
        ushort4 o;
        o.x = f2bf(v.x); o.y = f2bf(v.y); o.z = f2bf(v.z); o.w = f2bf(v.w);
        ((ushort4*)out)[i] = o;
    }
}

__global__ void cvt_w4(const float* __restrict__ a, const float* __restrict__ b,
                       const float* __restrict__ c, const float* __restrict__ d,
                       ushort* __restrict__ oq, ushort* __restrict__ ow) {
    const int N4 = 262144;
    int i = blockIdx.x * blockDim.x + threadIdx.x;
    int stride = gridDim.x * blockDim.x;
    for (; i < 4 * N4; i += stride) {
        int sel = i >> 18, local = i & (N4 - 1);
        const float* src = (sel == 0) ? a : (sel == 1) ? b : (sel == 2) ? c : d;
        float4 v = ((const float4*)src)[local];
        ushort4 o;
        o.x = f2bf(v.x); o.y = f2bf(v.y); o.z = f2bf(v.z); o.w = f2bf(v.w);
        if (sel < 3) ((ushort4*)oq)[sel * N4 + local] = o;
        else         ((ushort4*)ow)[local] = o;
    }
}

// ---------------- 2-phase pipelined bf16 GEMM: C[M,N] = A @ Bt^T + bias ----------------
// 256x128 tile, 512 thr (8 waves 4Mx2N, 64x64/wave), BK=64, 2-stage dbuf (96KB),
// counted vmcnt(6), 8-way source-side LDS swizzle (2-way on read = free).
// K-step: {vm;bar; ds kk0+kk1; MFMA kk0} {lgkm;bar; stage t+2; MFMA kk1}.
// MODE 0: QKV-cat bf16 out (Q pre-scaled); MODE 1: f32 out + bias0.
template<int MODE>
__global__ __launch_bounds__(512, 2)
void gemm_p2(const ushort* __restrict__ A, const ushort* __restrict__ Bt,
             const float* __restrict__ bias0, const float* __restrict__ bias1,
             const float* __restrict__ bias2,
             ushort* __restrict__ outb, float* __restrict__ outf,
             int M, int N, int K) {
    // per stage: A 256x64 = 16384 ush, B 128x64 = 8192 ush; 2 stages = 96KB
    __shared__ ushort lds[49152];
    const int t = threadIdx.x, lane = t & 63, w = t >> 6;
    const int wm = w >> 1, wn = w & 1;
    const int l15 = lane & 15, lg = lane >> 4;
    const int sw7 = l15 & 7;

    const int nbx = N >> 7;
    const int nwg = nbx * (M >> 8);
    const int bid = blockIdx.y * nbx + blockIdx.x;
    const int swz = (bid & 7) * (nwg >> 3) + (bid >> 3);
    const int m0 = (swz / nbx) * 256, n0 = (swz % nbx) * 128;

    // staging: 6 slots of 8KB (4 A + 2 B); thread covers row_in_slot = t>>3... per
    // wave: rows slot*64 + w*8 + (lane>>3), phys colblk = lane&7, global colblk
    // = (lane&7) ^ (lane>>3)  [source-side swizzle; dest linear].
    const int srow = lane >> 3;                 // 0..7
    const int gcb = (lane & 7) ^ srow;          // pre-swizzled global colblk
    const ushort* gsrc[6];
#pragma unroll
    for (int s = 0; s < 4; s++)
        gsrc[s] = A + (size_t)(m0 + s * 64 + w * 8 + srow) * K + gcb * 8;
#pragma unroll
    for (int s = 0; s < 2; s++)
        gsrc[4 + s] = Bt + (size_t)(n0 + s * 64 + w * 8 + srow) * K + gcb * 8;

#define STAGE(ST, KT) { \
    ushort* dst = &lds[(ST) * 24576 + w * 512]; \
    gload16(gsrc[0] + (KT) * 64, dst); \
    gload16(gsrc[1] + (KT) * 64, dst + 4096); \
    gload16(gsrc[2] + (KT) * 64, dst + 8192); \
    gload16(gsrc[3] + (KT) * 64, dst + 12288); \
    gload16(gsrc[4] + (KT) * 64, dst + 16384); \
    gload16(gsrc[5] + (KT) * 64, dst + 20480); }

    f32x4 acc[4][4] = {};
    const int NT = K >> 6;

    STAGE(0, 0); STAGE(1, 1);

    for (int kt = 0; kt < NT; ++kt) {
        if (kt < NT - 1) asm volatile("s_waitcnt vmcnt(6)" ::: "memory");
        else             asm volatile("s_waitcnt vmcnt(0)" ::: "memory");
        blockbar();

        const ushort* stg = &lds[(kt & 1) * 24576];
        bf16x8 a0[4], b0[4], a1[4], b1[4];
#pragma unroll
        for (int mi = 0; mi < 4; mi++) {
            int row = wm * 64 + mi * 16 + l15;
            a0[mi] = *(const bf16x8*)&stg[row * 64 + ((lg ^ sw7) << 3)];
            a1[mi] = *(const bf16x8*)&stg[row * 64 + (((4 + lg) ^ sw7) << 3)];
        }
#pragma unroll
        for (int ni = 0; ni < 4; ni++) {
            int row = wn * 64 + ni * 16 + l15;
            b0[ni] = *(const bf16x8*)&stg[16384 + row * 64 + ((lg ^ sw7) << 3)];
            b1[ni] = *(const bf16x8*)&stg[16384 + row * 64 + (((4 + lg) ^ sw7) << 3)];
        }

        __builtin_amdgcn_s_setprio(1);
#pragma unroll
        for (int mi = 0; mi < 4; mi++)
#pragma unroll
            for (int ni = 0; ni < 4; ni++)
                acc[mi][ni] = __builtin_amdgcn_mfma_f32_16x16x32_bf16(a0[mi], b0[ni], acc[mi][ni], 0, 0, 0);
        __builtin_amdgcn_s_setprio(0);

        asm volatile("s_waitcnt lgkmcnt(0)" ::: "memory");
        blockbar();
        if (kt + 2 < NT) STAGE((kt & 1), kt + 2);

        __builtin_amdgcn_s_setprio(1);
#pragma unroll
        for (int mi = 0; mi < 4; mi++)
#pragma unroll
            for (int ni = 0; ni < 4; ni++)
                acc[mi][ni] = __builtin_amdgcn_mfma_f32_16x16x32_bf16(a1[mi], b1[ni], acc[mi][ni], 0, 0, 0);
        __builtin_amdgcn_s_setprio(0);
    }
#undef STAGE

#pragma unroll
    for (int mi = 0; mi < 4; mi++)
#pragma unroll
        for (int ni = 0; ni < 4; ni++)
#pragma unroll
            for (int r = 0; r < 4; r++) {
                int gm = m0 + wm * 64 + mi * 16 + lg * 4 + r;
                int gn = n0 + wn * 64 + ni * 16 + l15;
                if (MODE == 0) {
                    const float* bp = (gn < 1024) ? bias0 : ((gn < 2048) ? bias1 : bias2);
                    float v = acc[mi][ni][r] + bp[gn & 1023];
                    if (gn < 1024) v *= 0.18033688011f;  // 0.125 * log2(e)
                    int proj = gn >> 10, nn = gn & 1023;
                    int h = nn >> 6, d = nn & 63;
                    int b = gm >> 11, s = gm & 2047;
                    outb[(size_t)proj * 8388608 + ((((size_t)b << 4) + h) * 2048 + s) * 64 + d] = f2bf(v);
                } else {
                    outf[(size_t)gm * N + gn] = acc[mi][ni][r] + bias0[gn];
                }
            }
}

// ---------------- causal flash attention (unchanged from round 9) ----------------
__global__ __launch_bounds__(256, 3)
void attn_fwd(const ushort* __restrict__ Qb, const ushort* __restrict__ Kb,
              const ushort* __restrict__ Vb, ushort* __restrict__ Ab) {
    constexpr int S = 2048;
    __shared__ ushort lds[16384];

    const int bid = blockIdx.x;
    const int qt = 15 - (bid >> 6);
    const int bh = bid & 63;
    const int b = bh >> 4, h = bh & 15;
    const ushort* Qp = Qb + (size_t)bh * S * 64;
    const ushort* Kp = Kb + (size_t)bh * S * 64;
    const ushort* Vp = Vb + (size_t)bh * S * 64;

    const int t = threadIdx.x, lane = t & 63, w = t >> 6;
    const int l15 = lane & 15, l31 = lane & 31, hi = lane >> 5, g = lane >> 4;

    int koff[2], voff[2];
#pragma unroll
    for (int i = 0; i < 2; i++) {
        int row = (w * 2 + i) * 8 + (lane >> 3);
        int gg = (lane & 7) ^ ((row ^ (row >> 3)) & 7);
        koff[i] = row * 64 + gg * 8;
    }
#pragma unroll
    for (int it = 0; it < 2; it++) {
        int T = (it * 4 + w) * 64 + lane;
        int kvb = T >> 5, db = (T >> 3) & 3, kvr = (T >> 1) & 3, dh = T & 1;
        voff[it] = (kvb * 4 + kvr) * 64 + db * 16 + dh * 8;
    }
    const unsigned vtbase = (unsigned)(uintptr_t)&lds[8192]
                          + (hi << 10) + ((g & 1) << 7) + (l15 << 3);

    auto stage = [&](int phase, int k0) {
#pragma unroll
        for (int i = 0; i < 2; i++)
            gload16(Kp + (size_t)k0 * 64 + koff[i], &lds[(phase << 12) + ((w * 2 + i) << 9)]);
#pragma unroll
        for (int it = 0; it < 2; it++)
            gload16(Vp + (size_t)k0 * 64 + voff[it], &lds[8192 + (phase << 12) + (((it << 2) + w) << 9)]);
    };

    const int fb = qt * 128 + w * 32;
    const int nt = 2 * qt + 2;

    bf16x8 qf[4];
#pragma unroll
    for (int kc = 0; kc < 4; kc++)
        qf[kc] = *(const bf16x8*)&Qp[(size_t)(fb + l31) * 64 + kc * 16 + hi * 8];

    float m = -3e38f, ls = 0.f;
    f32x16 O0 = {}, O1 = {};

    stage(0, 0);

    for (int tile = 0; tile < nt; tile++) {
        const int phase = tile & 1;
        const int k0 = tile * 64;
        if (tile + 1 < nt) {
            stage(phase ^ 1, (tile + 1) * 64);
            asm volatile("s_waitcnt vmcnt(4)" ::: "memory");
        } else {
            asm volatile("s_waitcnt vmcnt(0)" ::: "memory");
        }
        blockbar();

        if (k0 <= fb + 31) {
            const ushort* Kc = &lds[phase << 12];
            f32x16 s0 = {}, s1 = {};
            {
                bf16x8 kf[4];
#pragma unroll
                for (int kc = 0; kc < 4; kc++) {
                    int row = l31;
                    int sw = (row ^ (row >> 3)) & 7;
                    kf[kc] = *(const bf16x8*)&Kc[row * 64 + (((kc * 2 + hi) ^ sw) << 3)];
                }
                __builtin_amdgcn_s_setprio(1);
#pragma unroll
                for (int kc = 0; kc < 4; kc++)
                    s0 = __builtin_amdgcn_mfma_f32_32x32x16_bf16(kf[kc], qf[kc], s0, 0, 0, 0);
                __builtin_amdgcn_s_setprio(0);
            }
            {
                bf16x8 kf[4];
#pragma unroll
                for (int kc = 0; kc < 4; kc++) {
                    int row = 32 + l31;
                    int sw = (row ^ (row >> 3)) & 7;
                    kf[kc] = *(const bf16x8*)&Kc[row * 64 + (((kc * 2 + hi) ^ sw) << 3)];
                }
                __builtin_amdgcn_s_setprio(1);
#pragma unroll
                for (int kc = 0; kc < 4; kc++)
                    s1 = __builtin_amdgcn_mfma_f32_32x32x16_bf16(kf[kc], qf[kc], s1, 0, 0, 0);
                __builtin_amdgcn_s_setprio(0);
            }

            float pv[32];
            const bool diag = (k0 + 63 > fb);
            const int rel = fb + l31 - k0 - 4 * hi;
#pragma unroll
            for (int r = 0; r < 16; r++) {
                float v0 = s0[r], v1 = s1[r];
                if (diag) {
                    int kvc = (r & 3) + 8 * (r >> 2);
                    if (kvc > rel)      v0 = -1e30f;
                    if (kvc + 32 > rel) v1 = -1e30f;
                }
                pv[r] = v0; pv[16 + r] = v1;
            }
            float mx[16];
#pragma unroll
            for (int i = 0; i < 16; i++) mx[i] = fmaxf(pv[i], pv[i + 16]);
#pragma unroll
            for (int sgap = 8; sgap >= 1; sgap >>= 1)
#pragma unroll
                for (int i = 0; i < sgap; i++) mx[i] = fmaxf(mx[i], mx[i + sgap]);
            float pmax = fmaxf(mx[0], __shfl_xor(mx[0], 32));

            if (!__all(pmax <= m + 8.f)) {
                float mnew = fmaxf(m, pmax);
                float a = fexp2(m - mnew);
                ls *= a;
                float ar[16];
#pragma unroll
                for (int r = 0; r < 16; r++)
                    ar[r] = __shfl(a, (r & 3) + 8 * (r >> 2) + 4 * hi, 32);
#pragma unroll
                for (int r = 0; r < 16; r++) { O0[r] *= ar[r]; O1[r] *= ar[r]; }
                m = mnew;
            }
#pragma unroll
            for (int i = 0; i < 32; i++) pv[i] = fexp2(pv[i] - m);
            float sm[16];
#pragma unroll
            for (int i = 0; i < 16; i++) sm[i] = pv[i] + pv[i + 16];
#pragma unroll
            for (int sgap = 8; sgap >= 1; sgap >>= 1)
#pragma unroll
                for (int i = 0; i < sgap; i++) sm[i] += sm[i + sgap];
            ls += sm[0] + __shfl_xor(sm[0], 32);

            union PAu { bf16x8 v; unsigned wd[4]; } PA[4];
#pragma unroll
            for (int ks = 0; ks < 4; ks++)
#pragma unroll
                for (int i = 0; i < 2; i++) {
                    unsigned xw = cvtpk(pv[8 * ks + 2 * i], pv[8 * ks + 2 * i + 1]);
                    unsigned yw = cvtpk(pv[8 * ks + 2 * i + 4], pv[8 * ks + 2 * i + 5]);
                    asm("v_permlane32_swap_b32 %0, %1" : "+v"(xw), "+v"(yw));
                    PA[ks].wd[i] = xw; PA[ks].wd[2 + i] = yw;
                }

            const unsigned vtb = vtbase + (phase << 13);
            u32x2 vb[16];
#define TRR(idx, OFFSTR) asm volatile("ds_read_b64_tr_b16 %0, %1 offset:" OFFSTR : "=v"(vb[idx]) : "v"(vtb))
            TRR(0, "0");    TRR(1, "512");  TRR(2, "2048"); TRR(3, "2560");
            TRR(4, "4096"); TRR(5, "4608"); TRR(6, "6144"); TRR(7, "6656");
            TRR(8, "256");  TRR(9, "768");  TRR(10, "2304"); TRR(11, "2816");
            TRR(12, "4352"); TRR(13, "4864"); TRR(14, "6400"); TRR(15, "6912");
#undef TRR
            union FragU { bf16x8 v; u32x2 hh[2]; };
            asm volatile("s_waitcnt lgkmcnt(8)" ::: "memory");
            __builtin_amdgcn_sched_barrier(0);
            __builtin_amdgcn_s_setprio(1);
#pragma unroll
            for (int ks = 0; ks < 4; ks++) {
                FragU f; f.hh[0] = vb[ks * 2]; f.hh[1] = vb[ks * 2 + 1];
                O0 = __builtin_amdgcn_mfma_f32_32x32x16_bf16(PA[ks].v, f.v, O0, 0, 0, 0);
            }
            __builtin_amdgcn_s_setprio(0);
            asm volatile("s_waitcnt lgkmcnt(0)" ::: "memory");
            __builtin_amdgcn_sched_barrier(0);
            __builtin_amdgcn_s_setprio(1);
#pragma unroll
            for (int ks = 0; ks < 4; ks++) {
                FragU f; f.hh[0] = vb[8 + ks * 2]; f.hh[1] = vb[8 + ks * 2 + 1];
                O1 = __builtin_amdgcn_mfma_f32_32x32x16_bf16(PA[ks].v, f.v, O1, 0, 0, 0);
            }
            __builtin_amdgcn_s_setprio(0);
        }
        blockbar();
    }

    float inv[16];
#pragma unroll
    for (int r = 0; r < 16; r++)
        inv[r] = __builtin_amdgcn_rcpf(__shfl(ls, (r & 3) + 8 * (r >> 2) + 4 * hi, 32));
#pragma unroll
    for (int r = 0; r < 16; r++) {
        int q = fb + (r & 3) + 8 * (r >> 2) + 4 * hi;
        size_t base = ((size_t)b * 2048 + q) * 1024 + h * 64;
        Ab[base + l31]      = f2bf(O0[r] * inv[r]);
        Ab[base + 32 + l31] = f2bf(O1[r] * inv[r]);
    }
}

// ---------------- launch ----------------
extern "C" void kernel_launch(void* const* d_in, const int* in_sizes, int n_in,
                              void* d_out, int out_size, void* d_ws, size_t ws_size,
                              hipStream_t stream) {
    const float* query = (const float*)d_in[0];
    const float* Wq = (const float*)d_in[2];
    const float* bq = (const float*)d_in[3];
    const float* Wk = (const float*)d_in[4];
    const float* bk = (const float*)d_in[5];
    const float* Wv = (const float*)d_in[6];
    const float* bv = (const float*)d_in[7];
    const float* Wo = (const float*)d_in[8];
    const float* bo = (const float*)d_in[9];
    float* out = (float*)d_out;

    char* ws = (char*)d_ws;
    const size_t SZ_X = 8192ull * 1024 * 2;
    const size_t SZ_W = 1024ull * 1024 * 2;
    ushort* Xb   = (ushort*)(ws);
    ushort* Wcat = (ushort*)(ws + SZ_X);
    ushort* Wob  = (ushort*)(ws + SZ_X + 3 * SZ_W);
    ushort* QKVb = (ushort*)(ws + SZ_X + 4 * SZ_W);
    ushort* Ab   = (ushort*)(ws + 4 * SZ_X + 4 * SZ_W);

    cvt_f32_bf16<<<1024, 256, 0, stream>>>(query, Xb, 8192 * 1024 / 4);
    cvt_w4<<<1024, 256, 0, stream>>>(Wq, Wk, Wv, Wo, Wcat, Wob);

    gemm_p2<0><<<dim3(3072 / 128, 8192 / 256), 512, 0, stream>>>(
        Xb, Wcat, bq, bk, bv, QKVb, nullptr, 8192, 3072, 1024);

    attn_fwd<<<1024, 256, 0, stream>>>(QKVb, QKVb + 8388608, QKVb + 2 * 8388608, Ab);

    gemm_p2<1><<<dim3(1024 / 128, 8192 / 256), 512, 0, stream>>>(
        Ab, Wob, bo, nullptr, nullptr, nullptr, out, 8192, 1024, 1024);
}